// Round 6
// baseline (201.664 us; speedup 1.0000x reference)
//
#include <hip/hip_runtime.h>
#include <hip/hip_bf16.h>
#include <math.h>

#define Gn 16
#define Nn 256
#define Kf 128
#define Hh 32
#define Dd 768
#define NEG_BIG (-3.0e38f)
#define INV_A 0.3989422804014327f            // 1/2.5066256735058273
#define NHALF_LOG2E (-0.7213475204444817f)   // -0.5*log2(e)
#define GELU_C (-2.4554669f)                 // -1.702*log2(e)

typedef __attribute__((ext_vector_type(8))) short bf16x8;
typedef __attribute__((ext_vector_type(4))) float f32x4;

static __device__ __forceinline__ float fast_exp2(float x) {
#if __has_builtin(__builtin_amdgcn_exp2f)
    return __builtin_amdgcn_exp2f(x);
#else
    return exp2f(x);
#endif
}
static __device__ __forceinline__ float fast_rcp(float x) {
#if __has_builtin(__builtin_amdgcn_rcpf)
    return __builtin_amdgcn_rcpf(x);
#else
    return 1.0f / x;
#endif
}

static __device__ __forceinline__ unsigned short f2bf(float f) {
    union { float f; unsigned int u; } v; v.f = f;
    unsigned int r = v.u + 0x7FFF + ((v.u >> 16) & 1);   // RTNE
    return (unsigned short)(r >> 16);
}

// ---------------------------------------------------------------------------
// Prep: plain transposes w1t[n][k] = w1[k][n], w2t[m][k] = w2[k][m] (bf16),
// plus per-(g,k) gaussian coefficient table {mean, Ak, Ck}.
// ---------------------------------------------------------------------------
__global__ __launch_bounds__(256)
void prep_kernel(const float* __restrict__ w1, const float* __restrict__ w2,
                 const int* __restrict__ tarr, const float* __restrict__ means,
                 const float* __restrict__ stds,
                 unsigned short* __restrict__ w1t, unsigned short* __restrict__ w2t,
                 float4* __restrict__ coef)
{
    const int idx = blockIdx.x * 256 + threadIdx.x;
    if (idx < Kf * Kf) {                          // w1t: n-major
        const int n = idx >> 7, k = idx & 127;
        w1t[idx] = f2bf(w1[k * Kf + n]);
    } else if (idx < Kf * Kf + Hh * Kf) {         // w2t: m-major
        const int e = idx - Kf * Kf;
        const int m = e >> 7, k = e & 127;
        w2t[e] = f2bf(w2[k * Hh + m]);
    } else if (idx < Kf * Kf + Hh * Kf + Gn * Kf) {  // coef: (g, k)
        const int e = idx - (Kf * Kf + Hh * Kf);
        const int g = e >> 7, k = e & 127;
        const int tg = tarr[g];
        const float mean = means[tg * Kf + k];
        const float sd   = fabsf(stds[tg * Kf + k]) + 1e-5f;
        const float inv  = 1.0f / sd;
        coef[g * Kf + k] =
            make_float4(mean, NHALF_LOG2E * inv * inv, log2f(inv * INV_A), 0.f);
    }
}

// ---------------------------------------------------------------------------
// Attn: block per (g, i, j-half of 128). Wave wq owns j-quadrant [32wq,+32)
// through phase1 (ef gen), GEMM1 B-frags, h-write, GEMM2 — so the entire
// GEMM1->GELU->GEMM2 body is barrier-free. A-operands (w1t/w2t) load
// directly from global (L2/L1-resident). LDS 37.2KB -> 4 blocks/CU.
// LDS XOR swizzle: byte ^= ((row&7)<<4) within each 256B row.
// ---------------------------------------------------------------------------
__global__ __launch_bounds__(256, 4)
void graph3d_attn_kernel(const float* __restrict__ pos,
                         const int* __restrict__ atoms,
                         const float* __restrict__ mul_w,
                         const float* __restrict__ bias_w,
                         const float* __restrict__ b1,
                         const float* __restrict__ b2,
                         const unsigned short* __restrict__ w1t,
                         const unsigned short* __restrict__ w2t,
                         const float4* __restrict__ coef,
                         float* __restrict__ ws_sum,
                         float* __restrict__ out_dist,
                         float* __restrict__ out_delta,
                         float* __restrict__ out_attn)
{
    const int tid  = threadIdx.x;
    const int half = blockIdx.x;       // j-half: 0 or 1
    const int i    = blockIdx.y;
    const int g    = blockIdx.z;
    const int j0   = half * 128;

    __shared__ __align__(16) unsigned short s_tile[128 * 128];  // ef then h
    __shared__ float2 s_xgm[128];       // {xg, keep}
    __shared__ __align__(16) float s_b1[128];
    __shared__ float  s_b2[32];
    __shared__ __align__(8) float s_mean[128];
    __shared__ __align__(8) float s_Ak[128];
    __shared__ __align__(8) float s_Ck[128];
    __shared__ __align__(8) float s_part[4][128];

    const int lane = tid & 63, wq = tid >> 6;
    const int l15 = lane & 15, lhi = lane >> 4;

    // ---- phase 0: coeffs/biases, dist/delta/xg ----
    const int ai = atoms[g * Nn + i];
    float pix = pos[(g * Nn + i) * 3 + 0];
    float piy = pos[(g * Nn + i) * 3 + 1];
    float piz = pos[(g * Nn + i) * 3 + 2];
    if (ai == 0) { pix = 0.f; piy = 0.f; piz = 0.f; }

    if (tid < 128) {
        const float4 c = coef[g * Kf + tid];
        s_mean[tid] = c.x; s_Ak[tid] = c.y; s_Ck[tid] = c.z;
        s_b1[tid]   = b1[tid];

        const int j  = j0 + tid;
        const int aj = atoms[g * Nn + j];
        float pjx = pos[(g * Nn + j) * 3 + 0];
        float pjy = pos[(g * Nn + j) * 3 + 1];
        float pjz = pos[(g * Nn + j) * 3 + 2];
        if (aj == 0) { pjx = 0.f; pjy = 0.f; pjz = 0.f; }
        const float dx = pjx - pix, dy = pjy - piy, dz = pjz - piz;
        const float sq = dx * dx + dy * dy + dz * dz;
        const float dist = (sq > 0.f) ? sqrtf(sq) : 0.f;
        const float inv_d = 1.f / (dist + 1e-5f);
        const size_t base = (size_t)(g * Nn + i) * Nn + j;
        out_dist[base] = dist;
        out_delta[base * 3 + 0] = dx * inv_d;
        out_delta[base * 3 + 1] = dy * inv_d;
        out_delta[base * 3 + 2] = dz * inv_d;
        const int et = ai * 128 + aj;
        const float xg = fmaf(mul_w[et], dist, bias_w[et]);
        s_xgm[tid] = make_float2(xg, (aj == 0) ? 0.f : 1.f);
    } else if (tid < 160) {
        s_b2[tid - 128] = b2[tid - 128];
    }
    __syncthreads();

    // ---- phase 1: ef pairs -> bf16 tile (packed b32 writes) + fp32 j-sum ----
    {
        const int k2 = tid & 63;           // k-pair
        const int jq = tid >> 6;           // own j-quadrant
        const float2 mn = *(const float2*)&s_mean[2 * k2];
        const float2 Ak = *(const float2*)&s_Ak[2 * k2];
        const float2 Ck = *(const float2*)&s_Ck[2 * k2];
        float psum0 = 0.f, psum1 = 0.f;
        const int jb = jq * 32;
        const int colb = 4 * k2;
#pragma unroll 8
        for (int j = jb; j < jb + 32; ++j) {
            const float2 xm = s_xgm[j];
            const float d0 = xm.x - mn.x;
            const float d1 = xm.x - mn.y;
            const float e0 = fast_exp2(fmaf(Ak.x, d0 * d0, Ck.x));
            const float e1 = fast_exp2(fmaf(Ak.y, d1 * d1, Ck.y));
            psum0 = fmaf(e0, xm.y, psum0);
            psum1 = fmaf(e1, xm.y, psum1);
            const __hip_bfloat162 p = __float22bfloat162_rn(make_float2(e0, e1));
            *(unsigned int*)((char*)s_tile + j * 256 + (colb ^ ((j & 7) << 4))) =
                *(const unsigned int*)&p;
        }
        *(float2*)&s_part[jq][2 * k2] = make_float2(psum0, psum1);
    }
    __syncthreads();                       // s_part complete (cross-wave)
    if (tid < 128) {
        ws_sum[((size_t)(g * Nn + i) * 2 + half) * Kf + tid] =
            (s_part[0][tid] + s_part[1][tid]) + (s_part[2][tid] + s_part[3][tid]);
    }

    // ---- phase 2: GEMM1  D1[n][j] = w1^T x ef^T, A from global ----
    const int jrow0 = wq * 32 + l15;
    const int jrow1 = jrow0 + 16;
    const unsigned short* w1p = w1t + l15 * Kf + lhi * 8;   // + n16*2048 + ks*32

    f32x4 acc[8][2];
#pragma unroll
    for (int a = 0; a < 8; ++a)
#pragma unroll
        for (int b = 0; b < 2; ++b) acc[a][b] = (f32x4){0.f, 0.f, 0.f, 0.f};

#pragma unroll
    for (int ks = 0; ks < 4; ++ks) {
        const int kb = ks * 64 + lhi * 16;
        const bf16x8 b0 = *(const bf16x8*)((char*)s_tile + jrow0 * 256 + (kb ^ ((jrow0 & 7) << 4)));
        const bf16x8 b1f = *(const bf16x8*)((char*)s_tile + jrow1 * 256 + (kb ^ ((jrow1 & 7) << 4)));
#pragma unroll
        for (int nf = 0; nf < 8; ++nf) {
            const bf16x8 a = *(const bf16x8*)(w1p + nf * 16 * Kf + ks * 32);
            acc[nf][0] = __builtin_amdgcn_mfma_f32_16x16x32_bf16(a, b0, acc[nf][0], 0, 0, 0);
            acc[nf][1] = __builtin_amdgcn_mfma_f32_16x16x32_bf16(a, b1f, acc[nf][1], 0, 0, 0);
        }
    }

    // GELU epilogue: +b1, exp2-sigmoid, pack 4 n -> ds_write_b64 (own rows)
#pragma unroll
    for (int nf = 0; nf < 8; ++nf) {
        const float4 bb = *(const float4*)&s_b1[nf * 16 + lhi * 4];
        const int colb = 32 * nf + 8 * lhi;
#pragma unroll
        for (int jf = 0; jf < 2; ++jf) {
            const int j = wq * 32 + jf * 16 + l15;
            float h[4];
#pragma unroll
            for (int r = 0; r < 4; ++r) {
                const float v = acc[nf][jf][r] + ((const float*)&bb)[r];
                const float sg = fast_rcp(1.0f + fast_exp2(GELU_C * v));
                h[r] = v * sg;
            }
            const __hip_bfloat162 p0 = __float22bfloat162_rn(make_float2(h[0], h[1]));
            const __hip_bfloat162 p1 = __float22bfloat162_rn(make_float2(h[2], h[3]));
            uint2 u;
            u.x = *(const unsigned int*)&p0;
            u.y = *(const unsigned int*)&p1;
            *(uint2*)((char*)s_tile + j * 256 + (colb ^ ((j & 7) << 4))) = u;
        }
    }
    // no barrier: h rows written/read by the same wave only (lgkmcnt orders)

    // ---- phase 3: GEMM2  D[m][j] = w2^T x h^T, A from global ----
    const unsigned short* w2p = w2t + l15 * Kf + lhi * 8;   // + mf*16*128 + ks*32
    f32x4 acc2[2][2];
#pragma unroll
    for (int a = 0; a < 2; ++a)
#pragma unroll
        for (int b = 0; b < 2; ++b) acc2[a][b] = (f32x4){0.f, 0.f, 0.f, 0.f};

#pragma unroll
    for (int ks = 0; ks < 4; ++ks) {
        const int kb = ks * 64 + lhi * 16;
        const bf16x8 bh0 = *(const bf16x8*)((char*)s_tile + jrow0 * 256 + (kb ^ ((jrow0 & 7) << 4)));
        const bf16x8 bh1 = *(const bf16x8*)((char*)s_tile + jrow1 * 256 + (kb ^ ((jrow1 & 7) << 4)));
#pragma unroll
        for (int mf = 0; mf < 2; ++mf) {
            const bf16x8 a2 = *(const bf16x8*)(w2p + mf * 16 * Kf + ks * 32);
            acc2[mf][0] = __builtin_amdgcn_mfma_f32_16x16x32_bf16(a2, bh0, acc2[mf][0], 0, 0, 0);
            acc2[mf][1] = __builtin_amdgcn_mfma_f32_16x16x32_bf16(a2, bh1, acc2[mf][1], 0, 0, 0);
        }
    }

    // epilogue: +b2, pad mask, store [g][m][i][j]
    const size_t attn_g = (size_t)g * Hh * (Nn * Nn) + (size_t)i * Nn + j0;
#pragma unroll
    for (int mf = 0; mf < 2; ++mf) {
#pragma unroll
        for (int jf = 0; jf < 2; ++jf) {
            const int jloc = wq * 32 + jf * 16 + l15;
            const float keep = s_xgm[jloc].y;
#pragma unroll
            for (int r = 0; r < 4; ++r) {
                const int m = mf * 16 + lhi * 4 + r;
                float v = acc2[mf][jf][r] + s_b2[m];
                if (keep == 0.f) v = NEG_BIG;
                out_attn[attn_g + (size_t)m * (Nn * Nn) + jloc] = v;
            }
        }
    }
}

// ---------------------------------------------------------------------------
// Merge: [4096 x 128] @ we[128 x 768] + be, from ws partial sums (fp32).
// ---------------------------------------------------------------------------
__global__ __launch_bounds__(256)
void graph3d_merge_kernel(const float* __restrict__ ws_sum,
                          const float* __restrict__ we,
                          const float* __restrict__ be,
                          float* __restrict__ out_merge)
{
    const int tid = threadIdx.x;
    const int r0  = blockIdx.x * 16;
    __shared__ __align__(16) float s_rows[16][128];

#pragma unroll
    for (int p = 0; p < 8; ++p) {
        const int e = p * 256 + tid;
        const int r = e >> 7, k = e & 127;
        const size_t gi = (size_t)(r0 + r);
        s_rows[r][k] = ws_sum[(gi * 2 + 0) * Kf + k] + ws_sum[(gi * 2 + 1) * Kf + k];
    }
    __syncthreads();

    float acc[16][3];
#pragma unroll
    for (int r = 0; r < 16; ++r) { acc[r][0] = 0.f; acc[r][1] = 0.f; acc[r][2] = 0.f; }

    for (int k4 = 0; k4 < 32; ++k4) {
        const int k = k4 * 4;
        float w[4][3];
#pragma unroll
        for (int q = 0; q < 4; ++q) {
            w[q][0] = we[(k + q) * Dd + tid];
            w[q][1] = we[(k + q) * Dd + tid + 256];
            w[q][2] = we[(k + q) * Dd + tid + 512];
        }
#pragma unroll
        for (int r = 0; r < 16; ++r) {
            const float4 s = ((const float4*)&s_rows[r][0])[k4];
#pragma unroll
            for (int c = 0; c < 3; ++c) {
                acc[r][c] = fmaf(s.x, w[0][c], acc[r][c]);
                acc[r][c] = fmaf(s.y, w[1][c], acc[r][c]);
                acc[r][c] = fmaf(s.z, w[2][c], acc[r][c]);
                acc[r][c] = fmaf(s.w, w[3][c], acc[r][c]);
            }
        }
    }

    const float be0 = be[tid], be1 = be[tid + 256], be2 = be[tid + 512];
#pragma unroll
    for (int r = 0; r < 16; ++r) {
        const size_t ob = (size_t)(r0 + r) * Dd;
        out_merge[ob + tid]       = acc[r][0] + be0;
        out_merge[ob + tid + 256] = acc[r][1] + be1;
        out_merge[ob + tid + 512] = acc[r][2] + be2;
    }
}

// ---------------------------------------------------------------------------
extern "C" void kernel_launch(void* const* d_in, const int* in_sizes, int n_in,
                              void* d_out, int out_size, void* d_ws, size_t ws_size,
                              hipStream_t stream) {
    const float* pos    = (const float*)d_in[0];
    const int*   x      = (const int*)  d_in[1];
    const int*   t      = (const int*)  d_in[2];
    const float* means  = (const float*)d_in[3];
    const float* stds   = (const float*)d_in[4];
    const float* mul_w  = (const float*)d_in[5];
    const float* bias_w = (const float*)d_in[6];
    const float* w1     = (const float*)d_in[7];
    const float* b1     = (const float*)d_in[8];
    const float* w2     = (const float*)d_in[9];
    const float* b2     = (const float*)d_in[10];
    const float* we     = (const float*)d_in[11];
    const float* be     = (const float*)d_in[12];

    float* out = (float*)d_out;
    float* out_dist  = out;
    float* out_delta = out + (size_t)Gn * Nn * Nn;
    float* out_attn  = out + (size_t)Gn * Nn * Nn * 4;
    float* out_merge = out + (size_t)Gn * Nn * Nn * 4 + (size_t)Gn * Hh * Nn * Nn;

    // ws layout: fp32 sum partials [g][i][half][k] (4MB); w1t; w2t; coef
    float* ws_sum = (float*)d_ws;
    unsigned short* w1t = (unsigned short*)((char*)d_ws + (size_t)Gn * Nn * 2 * Kf * 4);
    unsigned short* w2t = w1t + Kf * Kf;
    float4* coef = (float4*)(w2t + Hh * Kf);

    prep_kernel<<<(Kf * Kf + Hh * Kf + Gn * Kf + 255) / 256, 256, 0, stream>>>(
        w1, w2, t, means, stds, w1t, w2t, coef);

    dim3 gridA(2, Nn, Gn);
    graph3d_attn_kernel<<<gridA, 256, 0, stream>>>(
        pos, x, mul_w, bias_w, b1, b2, w1t, w2t, coef,
        ws_sum, out_dist, out_delta, out_attn);

    graph3d_merge_kernel<<<(Gn * Nn) / 16, 256, 0, stream>>>(
        ws_sum, we, be, out_merge);
}

// Round 7
// 131.686 us; speedup vs baseline: 1.5314x; 1.5314x over previous
//
#include <hip/hip_runtime.h>
#include <hip/hip_bf16.h>
#include <math.h>

#define Gn 16
#define Nn 256
#define Kf 128
#define Hh 32
#define Dd 768
#define NEG_BIG (-3.0e38f)
#define INV_A 0.3989422804014327f            // 1/2.5066256735058273
#define NHALF_LOG2E (-0.7213475204444817f)   // -0.5*log2(e)
#define GELU_C (-2.4554669f)                 // -1.702*log2(e)

typedef __attribute__((ext_vector_type(8))) short bf16x8;
typedef __attribute__((ext_vector_type(4))) float f32x4;

static __device__ __forceinline__ float fast_exp2(float x) {
#if __has_builtin(__builtin_amdgcn_exp2f)
    return __builtin_amdgcn_exp2f(x);
#else
    return exp2f(x);
#endif
}
static __device__ __forceinline__ float fast_rcp(float x) {
#if __has_builtin(__builtin_amdgcn_rcpf)
    return __builtin_amdgcn_rcpf(x);
#else
    return 1.0f / x;
#endif
}

static __device__ __forceinline__ unsigned short f2bf(float f) {
    union { float f; unsigned int u; } v; v.f = f;
    unsigned int r = v.u + 0x7FFF + ((v.u >> 16) & 1);   // RTNE
    return (unsigned short)(r >> 16);
}

// 16B global -> LDS DMA. LDS dest is wave-uniform base + lane*16.
static __device__ __forceinline__ void load_lds16(const void* g, void* l) {
    __builtin_amdgcn_global_load_lds(
        (const __attribute__((address_space(1))) unsigned int*)g,
        (__attribute__((address_space(3))) unsigned int*)l, 16, 0, 0);
}

// Copy an 8KB pre-swizzled image into LDS: wave wq covers [wq*1024, +1024)
// and [4096 + wq*1024, +1024), lane-linear 16B chunks.
static __device__ __forceinline__ void stage8k(const char* gsrc, char* lbase,
                                               int wq, int lane) {
    const char* g0 = gsrc + wq * 1024 + lane * 16;
    char* l0 = lbase + wq * 1024 + lane * 16;
    load_lds16(g0, l0);
    load_lds16(g0 + 4096, l0 + 4096);
}

// ---------------------------------------------------------------------------
// Prep: pre-swizzled LDS images of w1 (4 x 8KB ks-chunks) and w2 (8KB, FULL
// 16 slots — r5 only wrote 8), plus per-(g,k) gaussian coefficients.
//  w1 chunk ks, row n, slot s (0..3), elem e: k = ks*32+s*8+e
//    byte = ks*8192 + n*64 + ((s ^ ((n>>1)&3))<<4) + 2e   [bank-fixed swizzle]
//  w2 row m (0..31), slot s2 (0..15), elem e: k = s2*8+e
//    byte = m*256 + ((s2 ^ (m&7))<<4) + 2e
// ---------------------------------------------------------------------------
__global__ __launch_bounds__(256)
void prep_kernel(const float* __restrict__ w1, const float* __restrict__ w2,
                 const int* __restrict__ tarr, const float* __restrict__ means,
                 const float* __restrict__ stds,
                 char* __restrict__ w1c, char* __restrict__ w2s,
                 float4* __restrict__ coef)
{
    const int idx = blockIdx.x * 256 + threadIdx.x;
    if (idx < 2048) {                    // w1 chunks: (ks, n, s)
        const int ks = idx >> 9;
        const int n  = (idx >> 2) & 127;
        const int s  = idx & 3;
        unsigned short v[8];
#pragma unroll
        for (int e = 0; e < 8; ++e) {
            const int k = ks * 32 + s * 8 + e;
            v[e] = f2bf(w1[k * Kf + n]);
        }
        *(uint4*)(w1c + ks * 8192 + n * 64 + ((s ^ ((n >> 1) & 3)) << 4)) =
            *(const uint4*)v;
    } else if (idx < 2560) {             // w2: (m, s2) — full 16 slots
        const int e2 = idx - 2048;
        const int m = e2 >> 4, s2 = e2 & 15;
        unsigned short v[8];
#pragma unroll
        for (int e = 0; e < 8; ++e) {
            const int k = s2 * 8 + e;
            v[e] = f2bf(w2[k * Hh + m]);
        }
        *(uint4*)(w2s + m * 256 + ((s2 ^ (m & 7)) << 4)) = *(const uint4*)v;
    } else if (idx < 4608) {             // coef: (g, k)
        const int e3 = idx - 2560;
        const int g = e3 >> 7, k = e3 & 127;
        const int tg = tarr[g];
        const float mean = means[tg * Kf + k];
        const float sd   = fabsf(stds[tg * Kf + k]) + 1e-5f;
        const float inv  = 1.0f / sd;
        coef[g * Kf + k] =
            make_float4(mean, NHALF_LOG2E * inv * inv, log2f(inv * INV_A), 0.f);
    }
}

// ---------------------------------------------------------------------------
// Attn: block per (g, i, j-half of 128). LDS = tile 32KB + chunk 8KB = 40960B
// exactly -> 4 blocks/CU. xg/keep live in registers (ballot masks + shfl);
// coef/b1/b2 read from global (L1-resident). Wave wq owns j-quadrant
// [32wq,+32) for GEMM B-frags / GELU / GEMM2 / stores; phase-1 is k-split
// (wave = 16 k-pairs, all 128 j) so the j-sum reduces inside the wave.
// Tile swizzle: byte ^= ((row&7)<<4) within each 256B row.
// ---------------------------------------------------------------------------
__global__ __launch_bounds__(256, 4)
void graph3d_attn_kernel(const float* __restrict__ pos,
                         const int* __restrict__ atoms,
                         const float* __restrict__ mul_w,
                         const float* __restrict__ bias_w,
                         const float* __restrict__ b1,
                         const float* __restrict__ b2,
                         const char* __restrict__ w1c,
                         const char* __restrict__ w2s,
                         const float4* __restrict__ coef,
                         float* __restrict__ ws_sum,
                         float* __restrict__ out_dist,
                         float* __restrict__ out_delta,
                         float* __restrict__ out_attn)
{
    const int tid  = threadIdx.x;
    const int half = blockIdx.x;       // j-half: 0 or 1
    const int i    = blockIdx.y;
    const int g    = blockIdx.z;
    const int j0   = half * 128;

    __shared__ __align__(16) unsigned short s_tile[128 * 128];  // ef then h
    __shared__ __align__(16) unsigned short s_chunk[4096];      // 8KB w1-chunk / w2

    const int lane = tid & 63, wq = tid >> 6;
    const int l15 = lane & 15, lhi = lane >> 4;

    // ---- phase 0: each lane computes j=lane and j=64+lane (per wave) ----
    const int ai = atoms[g * Nn + i];
    float pix = pos[(g * Nn + i) * 3 + 0];
    float piy = pos[(g * Nn + i) * 3 + 1];
    float piz = pos[(g * Nn + i) * 3 + 2];
    if (ai == 0) { pix = 0.f; piy = 0.f; piz = 0.f; }

    const int jA = lane, jB = lane + 64;
    const int aA = atoms[g * Nn + j0 + jA];
    const int aB = atoms[g * Nn + j0 + jB];
    float pax = pos[(g * Nn + j0 + jA) * 3 + 0];
    float pay = pos[(g * Nn + j0 + jA) * 3 + 1];
    float paz = pos[(g * Nn + j0 + jA) * 3 + 2];
    if (aA == 0) { pax = 0.f; pay = 0.f; paz = 0.f; }
    float pbx = pos[(g * Nn + j0 + jB) * 3 + 0];
    float pby = pos[(g * Nn + j0 + jB) * 3 + 1];
    float pbz = pos[(g * Nn + j0 + jB) * 3 + 2];
    if (aB == 0) { pbx = 0.f; pby = 0.f; pbz = 0.f; }

    const float dxA = pax - pix, dyA = pay - piy, dzA = paz - piz;
    const float sqA = dxA * dxA + dyA * dyA + dzA * dzA;
    const float dA  = (sqA > 0.f) ? sqrtf(sqA) : 0.f;
    const float ivA = 1.f / (dA + 1e-5f);
    const int  etA  = ai * 128 + aA;
    const float xgA = fmaf(mul_w[etA], dA, bias_w[etA]);

    const float dxB = pbx - pix, dyB = pby - piy, dzB = pbz - piz;
    const float sqB = dxB * dxB + dyB * dyB + dzB * dzB;
    const float dB  = (sqB > 0.f) ? sqrtf(sqB) : 0.f;
    const float ivB = 1.f / (dB + 1e-5f);
    const int  etB  = ai * 128 + aB;
    const float xgB = fmaf(mul_w[etB], dB, bias_w[etB]);

    const unsigned long long mA = __ballot(aA != 0);   // keep bits, j 0..63
    const unsigned long long mB = __ballot(aB != 0);   // keep bits, j 64..127

    // dist/delta stores: each j written once, by its owning quadrant's wave
    if (wq == (lane >> 5)) {
        const size_t base = (size_t)(g * Nn + i) * Nn + j0 + jA;
        out_dist[base] = dA;
        out_delta[base * 3 + 0] = dxA * ivA;
        out_delta[base * 3 + 1] = dyA * ivA;
        out_delta[base * 3 + 2] = dzA * ivA;
    } else if (wq == 2 + (lane >> 5)) {
        const size_t base = (size_t)(g * Nn + i) * Nn + j0 + jB;
        out_dist[base] = dB;
        out_delta[base * 3 + 0] = dxB * ivB;
        out_delta[base * 3 + 1] = dyB * ivB;
        out_delta[base * 3 + 2] = dzB * ivB;
    }

    // issue w1 chunk0 stage; drains under phase 1 (barrier waits vmcnt)
    stage8k(w1c, (char*)s_chunk, wq, lane);

    // ---- phase 1: ef -> bf16 tile + fp32 j-sum (wave = 16 k-pairs) ----
    {
        const int kpl = lane >> 2, jsub = lane & 3;
        const int kp  = wq * 16 + kpl;
        const float4 c0 = coef[g * Kf + 2 * kp];
        const float4 c1 = coef[g * Kf + 2 * kp + 1];
        const float xsrc = (jsub & 2) ? xgB : xgA;
        const unsigned long long msel = (jsub & 2) ? mB : mA;
        const unsigned int mm = (jsub & 1) ? (unsigned int)(msel >> 32)
                                           : (unsigned int)msel;
        const int sbase = (jsub & 1) * 32;
        char* rowb = (char*)s_tile + jsub * 32 * 256;
        unsigned int wa[8];
#pragma unroll
        for (int s = 0; s < 8; ++s) wa[s] = (unsigned int)(4 * kp) ^ (unsigned int)(s << 4);

        float ps0 = 0.f, ps1 = 0.f;
#pragma unroll
        for (int jj = 0; jj < 32; ++jj) {
            const float xgj = __shfl(xsrc, sbase + jj);
            const float kf  = (float)((mm >> jj) & 1u);
            const float d0 = xgj - c0.x;
            const float d1 = xgj - c1.x;
            const float e0 = fast_exp2(fmaf(c0.y, d0 * d0, c0.z));
            const float e1 = fast_exp2(fmaf(c1.y, d1 * d1, c1.z));
            ps0 = fmaf(e0, kf, ps0);
            ps1 = fmaf(e1, kf, ps1);
            const __hip_bfloat162 p = __float22bfloat162_rn(make_float2(e0, e1));
            *(unsigned int*)(rowb + jj * 256 + wa[jj & 7]) = *(const unsigned int*)&p;
        }
        // reduce over the 4 jsub lanes (adjacent), then one writer per k-pair
        ps0 += __shfl_xor(ps0, 1); ps0 += __shfl_xor(ps0, 2);
        ps1 += __shfl_xor(ps1, 1); ps1 += __shfl_xor(ps1, 2);
        if (jsub == 0)
            *(float2*)&ws_sum[((size_t)(g * Nn + i) * 2 + half) * Kf + 2 * kp] =
                make_float2(ps0, ps1);
    }
    __syncthreads();                       // tile complete + chunk0 staged

    // ---- phase 2: GEMM1  D1[n][j] = w1^T x ef^T (streamed 8KB chunks) ----
    const int jrow0 = wq * 32 + l15, jrow1 = jrow0 + 16;
    const char* tb0 = (const char*)s_tile + jrow0 * 256;
    const char* tb1 = (const char*)s_tile + jrow1 * 256;
    const int sw0 = (jrow0 & 7) << 4, sw1 = (jrow1 & 7) << 4;
    const int aoff = l15 * 64 + ((lhi ^ ((l15 >> 1) & 3)) << 4);  // conflict-free

    f32x4 acc[8][2];
#pragma unroll
    for (int a = 0; a < 8; ++a)
#pragma unroll
        for (int b = 0; b < 2; ++b) acc[a][b] = (f32x4){0.f, 0.f, 0.f, 0.f};

#pragma unroll
    for (int ks = 0; ks < 4; ++ks) {
        if (ks) __syncthreads();           // chunk ks staged (vmcnt drained)
        const int kb = ks * 64 + lhi * 16;
        const bf16x8 b0  = *(const bf16x8*)(tb0 + (kb ^ sw0));
        const bf16x8 b1f = *(const bf16x8*)(tb1 + (kb ^ sw1));
        bf16x8 a[8];
#pragma unroll
        for (int nf = 0; nf < 8; ++nf)
            a[nf] = *(const bf16x8*)((const char*)s_chunk + nf * 1024 + aoff);
        __syncthreads();                   // all waves done reading chunk ks
        if (ks < 3) stage8k(w1c + (ks + 1) * 8192, (char*)s_chunk, wq, lane);
        else        stage8k(w2s, (char*)s_chunk, wq, lane);
#pragma unroll
        for (int nf = 0; nf < 8; ++nf) {
            acc[nf][0] = __builtin_amdgcn_mfma_f32_16x16x32_bf16(a[nf], b0,  acc[nf][0], 0, 0, 0);
            acc[nf][1] = __builtin_amdgcn_mfma_f32_16x16x32_bf16(a[nf], b1f, acc[nf][1], 0, 0, 0);
        }
    }

    // GELU epilogue: +b1 (global, L1-hit), exp2-sigmoid, packed b64 writes
#pragma unroll
    for (int nf = 0; nf < 8; ++nf) {
        const float4 bb = *(const float4*)(b1 + nf * 16 + lhi * 4);
        const int colb = 32 * nf + 8 * lhi;
#pragma unroll
        for (int jf = 0; jf < 2; ++jf) {
            const char* tb = jf ? tb1 : tb0;
            const int sw = jf ? sw1 : sw0;
            float h[4];
#pragma unroll
            for (int r = 0; r < 4; ++r) {
                const float v = acc[nf][jf][r] + ((const float*)&bb)[r];
                const float sg = fast_rcp(1.0f + fast_exp2(GELU_C * v));
                h[r] = v * sg;
            }
            const __hip_bfloat162 p0 = __float22bfloat162_rn(make_float2(h[0], h[1]));
            const __hip_bfloat162 p1 = __float22bfloat162_rn(make_float2(h[2], h[3]));
            uint2 u;
            u.x = *(const unsigned int*)&p0;
            u.y = *(const unsigned int*)&p1;
            *(uint2*)(const_cast<char*>(tb) + (colb ^ sw)) = u;
        }
    }
    __syncthreads();                       // w2 image staged (vmcnt drained)

    // ---- phase 3: GEMM2  D[m][j] = w2^T x h^T ----
    f32x4 acc2[2][2];
#pragma unroll
    for (int a = 0; a < 2; ++a)
#pragma unroll
        for (int b = 0; b < 2; ++b) acc2[a][b] = (f32x4){0.f, 0.f, 0.f, 0.f};

#pragma unroll
    for (int ks = 0; ks < 4; ++ks) {
        const int kb = ks * 64 + lhi * 16;
        const bf16x8 bh0 = *(const bf16x8*)(tb0 + (kb ^ sw0));
        const bf16x8 bh1 = *(const bf16x8*)(tb1 + (kb ^ sw1));
#pragma unroll
        for (int mf = 0; mf < 2; ++mf) {
            const int m = mf * 16 + l15;
            const bf16x8 a2 = *(const bf16x8*)((const char*)s_chunk + m * 256 + (kb ^ ((m & 7) << 4)));
            acc2[mf][0] = __builtin_amdgcn_mfma_f32_16x16x32_bf16(a2, bh0, acc2[mf][0], 0, 0, 0);
            acc2[mf][1] = __builtin_amdgcn_mfma_f32_16x16x32_bf16(a2, bh1, acc2[mf][1], 0, 0, 0);
        }
    }

    // epilogue: +b2 (global), pad mask from ballot bits, store [g][m][i][j]
    const size_t attn_g = (size_t)g * Hh * (Nn * Nn) + (size_t)i * Nn + j0;
    const unsigned long long mOwn = (wq & 2) ? mB : mA;
#pragma unroll
    for (int jf = 0; jf < 2; ++jf) {
        const int jloc = wq * 32 + jf * 16 + l15;
        const int bit  = (wq & 1) * 32 + jf * 16 + l15;
        const bool keep = (mOwn >> bit) & 1ull;
#pragma unroll
        for (int mf = 0; mf < 2; ++mf) {
            const float4 b2v = *(const float4*)(b2 + mf * 16 + lhi * 4);
#pragma unroll
            for (int r = 0; r < 4; ++r) {
                const int m = mf * 16 + lhi * 4 + r;
                float v = acc2[mf][jf][r] + ((const float*)&b2v)[r];
                if (!keep) v = NEG_BIG;
                out_attn[attn_g + (size_t)m * (Nn * Nn) + jloc] = v;
            }
        }
    }
}

// ---------------------------------------------------------------------------
// Merge: [4096 x 128] @ we[128 x 768] + be.  Grid = 3 col-blocks x 256
// row-groups (768 blocks, 3/CU) — r5's 256-block version was latency-bound.
// ---------------------------------------------------------------------------
__global__ __launch_bounds__(256)
void graph3d_merge_kernel(const float* __restrict__ ws_sum,
                          const float* __restrict__ we,
                          const float* __restrict__ be,
                          float* __restrict__ out_merge)
{
    const int tid = threadIdx.x;
    const int bd  = blockIdx.x;          // column block: 0..2
    const int r0  = blockIdx.y * 16;     // row group
    __shared__ __align__(16) float s_rows[16][128];

#pragma unroll
    for (int p = 0; p < 8; ++p) {
        const int e = p * 256 + tid;
        const int r = e >> 7, k = e & 127;
        const size_t gi = (size_t)(r0 + r);
        s_rows[r][k] = ws_sum[(gi * 2 + 0) * Kf + k] + ws_sum[(gi * 2 + 1) * Kf + k];
    }
    __syncthreads();

    const int col = bd * 256 + tid;
    float acc[16];
#pragma unroll
    for (int r = 0; r < 16; ++r) acc[r] = 0.f;

    for (int k4 = 0; k4 < 32; ++k4) {
        const int k = k4 * 4;
        const float w0 = we[(k + 0) * Dd + col];
        const float w1v = we[(k + 1) * Dd + col];
        const float w2v = we[(k + 2) * Dd + col];
        const float w3 = we[(k + 3) * Dd + col];
#pragma unroll
        for (int r = 0; r < 16; ++r) {
            const float4 s = ((const float4*)&s_rows[r][0])[k4];
            acc[r] = fmaf(s.x, w0, acc[r]);
            acc[r] = fmaf(s.y, w1v, acc[r]);
            acc[r] = fmaf(s.z, w2v, acc[r]);
            acc[r] = fmaf(s.w, w3, acc[r]);
        }
    }

    const float b = be[col];
#pragma unroll
    for (int r = 0; r < 16; ++r)
        out_merge[(size_t)(r0 + r) * Dd + col] = acc[r] + b;
}

// ---------------------------------------------------------------------------
extern "C" void kernel_launch(void* const* d_in, const int* in_sizes, int n_in,
                              void* d_out, int out_size, void* d_ws, size_t ws_size,
                              hipStream_t stream) {
    const float* pos    = (const float*)d_in[0];
    const int*   x      = (const int*)  d_in[1];
    const int*   t      = (const int*)  d_in[2];
    const float* means  = (const float*)d_in[3];
    const float* stds   = (const float*)d_in[4];
    const float* mul_w  = (const float*)d_in[5];
    const float* bias_w = (const float*)d_in[6];
    const float* w1     = (const float*)d_in[7];
    const float* b1     = (const float*)d_in[8];
    const float* w2     = (const float*)d_in[9];
    const float* b2     = (const float*)d_in[10];
    const float* we     = (const float*)d_in[11];
    const float* be     = (const float*)d_in[12];

    float* out = (float*)d_out;
    float* out_dist  = out;
    float* out_delta = out + (size_t)Gn * Nn * Nn;
    float* out_attn  = out + (size_t)Gn * Nn * Nn * 4;
    float* out_merge = out + (size_t)Gn * Nn * Nn * 4 + (size_t)Gn * Hh * Nn * Nn;

    // ws: 4MB fp32 sum partials [g][i][half][k]; w1c 32KB; w2s 8KB; coef 32KB
    float* ws_sum = (float*)d_ws;
    char*  w1c  = (char*)d_ws + (size_t)Gn * Nn * 2 * Kf * 4;
    char*  w2s  = w1c + 4 * 8192;
    float4* coef = (float4*)(w2s + 8192);

    prep_kernel<<<18, 256, 0, stream>>>(w1, w2, t, means, stds, w1c, w2s, coef);

    dim3 gridA(2, Nn, Gn);
    graph3d_attn_kernel<<<gridA, 256, 0, stream>>>(
        pos, x, mul_w, bias_w, b1, b2, w1c, w2s, coef,
        ws_sum, out_dist, out_delta, out_attn);

    dim3 gridB(3, 256);
    graph3d_merge_kernel<<<gridB, 256, 0, stream>>>(
        ws_sum, we, be, out_merge);
}

// Round 8
// 129.181 us; speedup vs baseline: 1.5611x; 1.0194x over previous
//
#include <hip/hip_runtime.h>
#include <hip/hip_bf16.h>
#include <math.h>

#define Gn 16
#define Nn 256
#define Kf 128
#define Hh 32
#define Dd 768
#define NEG_BIG (-3.0e38f)
#define INV_A 0.3989422804014327f            // 1/2.5066256735058273
#define NHALF_LOG2E (-0.7213475204444817f)   // -0.5*log2(e)
#define GELU_C (-2.4554669f)                 // -1.702*log2(e)

typedef __attribute__((ext_vector_type(8))) short bf16x8;
typedef __attribute__((ext_vector_type(4))) float f32x4;

static __device__ __forceinline__ float fast_exp2(float x) {
#if __has_builtin(__builtin_amdgcn_exp2f)
    return __builtin_amdgcn_exp2f(x);
#else
    return exp2f(x);
#endif
}
static __device__ __forceinline__ float fast_rcp(float x) {
#if __has_builtin(__builtin_amdgcn_rcpf)
    return __builtin_amdgcn_rcpf(x);
#else
    return 1.0f / x;
#endif
}

static __device__ __forceinline__ unsigned short f2bf(float f) {
    union { float f; unsigned int u; } v; v.f = f;
    unsigned int r = v.u + 0x7FFF + ((v.u >> 16) & 1);   // RTNE
    return (unsigned short)(r >> 16);
}

// 16B global -> LDS DMA. LDS dest is wave-uniform base + lane*16.
static __device__ __forceinline__ void load_lds16(const void* g, void* l) {
    __builtin_amdgcn_global_load_lds(
        (const __attribute__((address_space(1))) unsigned int*)g,
        (__attribute__((address_space(3))) unsigned int*)l, 16, 0, 0);
}

// Copy an 8KB pre-swizzled image into LDS: wave wq covers [wq*1024, +1024)
// and [4096 + wq*1024, +1024), lane-linear 16B chunks.
static __device__ __forceinline__ void stage8k(const char* gsrc, char* lbase,
                                               int wq, int lane) {
    const char* g0 = gsrc + wq * 1024 + lane * 16;
    char* l0 = lbase + wq * 1024 + lane * 16;
    load_lds16(g0, l0);
    load_lds16(g0 + 4096, l0 + 4096);
}

// ---------------------------------------------------------------------------
// Prep: pre-swizzled LDS images of w1 (4 x 8KB ks-chunks, r5 slot swizzle)
// and w2 (8KB, full 16 slots), plus per-(g,k) gaussian coefficients.
//  w1 chunk ks, row n, slot s (0..3), elem e: k = ks*32+s*8+e
//    byte = ks*8192 + n*64 + ((s ^ (n&3))<<4) + 2e
//  w2 row m (0..31), slot s2 (0..15), elem e: k = s2*8+e
//    byte = m*256 + ((s2 ^ (m&7))<<4) + 2e
// ---------------------------------------------------------------------------
__global__ __launch_bounds__(256)
void prep_kernel(const float* __restrict__ w1, const float* __restrict__ w2,
                 const int* __restrict__ tarr, const float* __restrict__ means,
                 const float* __restrict__ stds,
                 char* __restrict__ w1c, char* __restrict__ w2s,
                 float4* __restrict__ coef)
{
    const int idx = blockIdx.x * 256 + threadIdx.x;
    if (idx < 2048) {                    // w1 chunks: (ks, n, s)
        const int ks = idx >> 9;
        const int n  = (idx >> 2) & 127;
        const int s  = idx & 3;
        unsigned short v[8];
#pragma unroll
        for (int e = 0; e < 8; ++e) {
            const int k = ks * 32 + s * 8 + e;
            v[e] = f2bf(w1[k * Kf + n]);
        }
        *(uint4*)(w1c + ks * 8192 + n * 64 + ((s ^ (n & 3)) << 4)) =
            *(const uint4*)v;
    } else if (idx < 2560) {             // w2: (m, s2) — full 16 slots
        const int e2 = idx - 2048;
        const int m = e2 >> 4, s2 = e2 & 15;
        unsigned short v[8];
#pragma unroll
        for (int e = 0; e < 8; ++e) {
            const int k = s2 * 8 + e;
            v[e] = f2bf(w2[k * Hh + m]);
        }
        *(uint4*)(w2s + m * 256 + ((s2 ^ (m & 7)) << 4)) = *(const uint4*)v;
    } else if (idx < 4608) {             // coef: (g, k)
        const int e3 = idx - 2560;
        const int g = e3 >> 7, k = e3 & 127;
        const int tg = tarr[g];
        const float mean = means[tg * Kf + k];
        const float sd   = fabsf(stds[tg * Kf + k]) + 1e-5f;
        const float inv  = 1.0f / sd;
        coef[g * Kf + k] =
            make_float4(mean, NHALF_LOG2E * inv * inv, log2f(inv * INV_A), 0.f);
    }
}

// ---------------------------------------------------------------------------
// Attn: block per (g, i, j-half of 128). LDS = tile 32KB + chunk 8KB = 40960B
// exactly -> 4 blocks/CU. Phase-1 uses the r5 conflict-free mapping
// (lane = k-pair across 64 dwords; wave = own j-quadrant) with xg via shfl
// from registers; partial k-sums ride in 2 VGPRs until the tile dies after
// GEMM2, then reduce through the tile. Register diet: A-frags in 2 groups
// of 4 so peak live ~= 64 AGPR + ~50 arch < 128 (no spill at 4 waves/SIMD).
// Tile swizzle: byte ^= ((row&7)<<4) within each 256B row.
// ---------------------------------------------------------------------------
__global__ __launch_bounds__(256, 4)
void graph3d_attn_kernel(const float* __restrict__ pos,
                         const int* __restrict__ atoms,
                         const float* __restrict__ mul_w,
                         const float* __restrict__ bias_w,
                         const float* __restrict__ b1,
                         const float* __restrict__ b2,
                         const char* __restrict__ w1c,
                         const char* __restrict__ w2s,
                         const float4* __restrict__ coef,
                         float* __restrict__ ws_sum,
                         float* __restrict__ out_dist,
                         float* __restrict__ out_delta,
                         float* __restrict__ out_attn)
{
    const int tid  = threadIdx.x;
    const int half = blockIdx.x;       // j-half: 0 or 1
    const int i    = blockIdx.y;
    const int g    = blockIdx.z;
    const int j0   = half * 128;

    __shared__ __align__(16) unsigned short s_tile[128 * 128];  // ef then h
    __shared__ __align__(16) unsigned short s_chunk[4096];      // 8KB w1-chunk / w2

    const int lane = tid & 63, wq = tid >> 6;
    const int l15 = lane & 15, lhi = lane >> 4;

    // ---- phase 0: each lane computes j=lane and j=64+lane (per wave) ----
    const int ai = atoms[g * Nn + i];
    float pix = pos[(g * Nn + i) * 3 + 0];
    float piy = pos[(g * Nn + i) * 3 + 1];
    float piz = pos[(g * Nn + i) * 3 + 2];
    if (ai == 0) { pix = 0.f; piy = 0.f; piz = 0.f; }

    const int jA = lane, jB = lane + 64;
    const int aA = atoms[g * Nn + j0 + jA];
    const int aB = atoms[g * Nn + j0 + jB];
    float pax = pos[(g * Nn + j0 + jA) * 3 + 0];
    float pay = pos[(g * Nn + j0 + jA) * 3 + 1];
    float paz = pos[(g * Nn + j0 + jA) * 3 + 2];
    if (aA == 0) { pax = 0.f; pay = 0.f; paz = 0.f; }
    float pbx = pos[(g * Nn + j0 + jB) * 3 + 0];
    float pby = pos[(g * Nn + j0 + jB) * 3 + 1];
    float pbz = pos[(g * Nn + j0 + jB) * 3 + 2];
    if (aB == 0) { pbx = 0.f; pby = 0.f; pbz = 0.f; }

    const float dxA = pax - pix, dyA = pay - piy, dzA = paz - piz;
    const float sqA = dxA * dxA + dyA * dyA + dzA * dzA;
    const float dA  = (sqA > 0.f) ? sqrtf(sqA) : 0.f;
    const float ivA = 1.f / (dA + 1e-5f);
    const int  etA  = ai * 128 + aA;
    const float xgA = fmaf(mul_w[etA], dA, bias_w[etA]);

    const float dxB = pbx - pix, dyB = pby - piy, dzB = pbz - piz;
    const float sqB = dxB * dxB + dyB * dyB + dzB * dzB;
    const float dB  = (sqB > 0.f) ? sqrtf(sqB) : 0.f;
    const float ivB = 1.f / (dB + 1e-5f);
    const int  etB  = ai * 128 + aB;
    const float xgB = fmaf(mul_w[etB], dB, bias_w[etB]);

    const unsigned long long mA = __ballot(aA != 0);   // keep bits, j 0..63
    const unsigned long long mB = __ballot(aB != 0);   // keep bits, j 64..127

    // dist/delta stores: each j written once, by its owning quadrant's wave
    if (wq == (lane >> 5)) {
        const size_t base = (size_t)(g * Nn + i) * Nn + j0 + jA;
        out_dist[base] = dA;
        out_delta[base * 3 + 0] = dxA * ivA;
        out_delta[base * 3 + 1] = dyA * ivA;
        out_delta[base * 3 + 2] = dzA * ivA;
    } else if (wq == 2 + (lane >> 5)) {
        const size_t base = (size_t)(g * Nn + i) * Nn + j0 + jB;
        out_dist[base] = dB;
        out_delta[base * 3 + 0] = dxB * ivB;
        out_delta[base * 3 + 1] = dyB * ivB;
        out_delta[base * 3 + 2] = dzB * ivB;
    }

    // issue w1 chunk0 stage; drains under phase 1 (barrier waits vmcnt)
    stage8k(w1c, (char*)s_chunk, wq, lane);

    // ---- phase 1: ef -> bf16 tile + fp32 partial j-sums (r5 mapping:
    //      lane = k-pair, wave = own j-quadrant; writes hit 64 consecutive
    //      dwords -> 2 lanes/bank, conflict-free) ----
    float ps0 = 0.f, ps1 = 0.f;
    {
        const int k2 = lane;               // k-pair index 0..63
        const float4 c0 = coef[g * Kf + 2 * k2];
        const float4 c1 = coef[g * Kf + 2 * k2 + 1];
        const float xsrc = (wq & 2) ? xgB : xgA;
        const unsigned long long msel = (wq & 2) ? mB : mA;
        const unsigned int mm = (wq & 1) ? (unsigned int)(msel >> 32)
                                         : (unsigned int)msel;
        const int sbase = (wq & 1) * 32;
        char* rowbase = (char*)s_tile + wq * 32 * 256;
        const int colb = 4 * k2;
#pragma unroll 8
        for (int jj = 0; jj < 32; ++jj) {
            const float xgj = __shfl(xsrc, sbase + jj);
            const float kf  = (float)((mm >> jj) & 1u);
            const float d0 = xgj - c0.x;
            const float d1 = xgj - c1.x;
            const float e0 = fast_exp2(fmaf(c0.y, d0 * d0, c0.z));
            const float e1 = fast_exp2(fmaf(c1.y, d1 * d1, c1.z));
            ps0 = fmaf(e0, kf, ps0);
            ps1 = fmaf(e1, kf, ps1);
            const __hip_bfloat162 p = __float22bfloat162_rn(make_float2(e0, e1));
            *(unsigned int*)(rowbase + jj * 256 + (colb ^ ((jj & 7) << 4))) =
                *(const unsigned int*)&p;
        }
    }
    __syncthreads();                       // tile complete + chunk0 staged

    // ---- phase 2: GEMM1  D1[n][j] = w1^T x ef^T (streamed 8KB chunks) ----
    const int jrow0 = wq * 32 + l15, jrow1 = jrow0 + 16;
    const char* tb0 = (const char*)s_tile + jrow0 * 256;
    const char* tb1 = (const char*)s_tile + jrow1 * 256;
    const int sw0 = (jrow0 & 7) << 4, sw1 = (jrow1 & 7) << 4;
    const int aoff = l15 * 64 + ((lhi ^ (l15 & 3)) << 4);

    f32x4 acc[8][2];
#pragma unroll
    for (int a = 0; a < 8; ++a)
#pragma unroll
        for (int b = 0; b < 2; ++b) acc[a][b] = (f32x4){0.f, 0.f, 0.f, 0.f};

#pragma unroll
    for (int ks = 0; ks < 4; ++ks) {
        if (ks) __syncthreads();           // chunk ks staged (vmcnt drained)
        const int kb = ks * 64 + lhi * 16;
        const bf16x8 b0  = *(const bf16x8*)(tb0 + (kb ^ sw0));
        const bf16x8 b1f = *(const bf16x8*)(tb1 + (kb ^ sw1));
        bf16x8 a0[4];
#pragma unroll
        for (int nf = 0; nf < 4; ++nf)
            a0[nf] = *(const bf16x8*)((const char*)s_chunk + nf * 1024 + aoff);
#pragma unroll
        for (int nf = 0; nf < 4; ++nf) {
            acc[nf][0] = __builtin_amdgcn_mfma_f32_16x16x32_bf16(a0[nf], b0,  acc[nf][0], 0, 0, 0);
            acc[nf][1] = __builtin_amdgcn_mfma_f32_16x16x32_bf16(a0[nf], b1f, acc[nf][1], 0, 0, 0);
        }
        bf16x8 a1[4];
#pragma unroll
        for (int nf = 0; nf < 4; ++nf)
            a1[nf] = *(const bf16x8*)((const char*)s_chunk + (nf + 4) * 1024 + aoff);
        __syncthreads();                   // all waves done reading chunk ks
        if (ks < 3) stage8k(w1c + (ks + 1) * 8192, (char*)s_chunk, wq, lane);
        else        stage8k(w2s, (char*)s_chunk, wq, lane);
#pragma unroll
        for (int nf = 0; nf < 4; ++nf) {
            acc[nf + 4][0] = __builtin_amdgcn_mfma_f32_16x16x32_bf16(a1[nf], b0,  acc[nf + 4][0], 0, 0, 0);
            acc[nf + 4][1] = __builtin_amdgcn_mfma_f32_16x16x32_bf16(a1[nf], b1f, acc[nf + 4][1], 0, 0, 0);
        }
    }

    // GELU epilogue: +b1 (global, L1-hit), exp2-sigmoid, packed b64 writes
#pragma unroll
    for (int nf = 0; nf < 8; ++nf) {
        const float4 bb = *(const float4*)(b1 + nf * 16 + lhi * 4);
        const int colb = 32 * nf + 8 * lhi;
#pragma unroll
        for (int jf = 0; jf < 2; ++jf) {
            const char* tb = jf ? tb1 : tb0;
            const int sw = jf ? sw1 : sw0;
            float h[4];
#pragma unroll
            for (int r = 0; r < 4; ++r) {
                const float v = acc[nf][jf][r] + ((const float*)&bb)[r];
                const float sg = fast_rcp(1.0f + fast_exp2(GELU_C * v));
                h[r] = v * sg;
            }
            const __hip_bfloat162 p0 = __float22bfloat162_rn(make_float2(h[0], h[1]));
            const __hip_bfloat162 p1 = __float22bfloat162_rn(make_float2(h[2], h[3]));
            uint2 u;
            u.x = *(const unsigned int*)&p0;
            u.y = *(const unsigned int*)&p1;
            *(uint2*)(const_cast<char*>(tb) + (colb ^ sw)) = u;
        }
    }
    __syncthreads();                       // w2 image staged (vmcnt drained)

    // ---- phase 3: GEMM2  D[m][j] = w2^T x h^T ----
    f32x4 acc2[2][2];
#pragma unroll
    for (int a = 0; a < 2; ++a)
#pragma unroll
        for (int b = 0; b < 2; ++b) acc2[a][b] = (f32x4){0.f, 0.f, 0.f, 0.f};

#pragma unroll
    for (int ks = 0; ks < 4; ++ks) {
        const int kb = ks * 64 + lhi * 16;
        const bf16x8 bh0 = *(const bf16x8*)(tb0 + (kb ^ sw0));
        const bf16x8 bh1 = *(const bf16x8*)(tb1 + (kb ^ sw1));
#pragma unroll
        for (int mf = 0; mf < 2; ++mf) {
            const int m = mf * 16 + l15;
            const bf16x8 a2 = *(const bf16x8*)((const char*)s_chunk + m * 256 + (kb ^ ((m & 7) << 4)));
            acc2[mf][0] = __builtin_amdgcn_mfma_f32_16x16x32_bf16(a2, bh0, acc2[mf][0], 0, 0, 0);
            acc2[mf][1] = __builtin_amdgcn_mfma_f32_16x16x32_bf16(a2, bh1, acc2[mf][1], 0, 0, 0);
        }
    }

    // ---- k-sum reduce through the (now dead) tile, then ws_sum ----
    __syncthreads();                       // all waves done reading tile
    {
        float* pt = (float*)s_tile;        // 2KB scratch: [wq][2*kp]
        *(float2*)&pt[wq * 128 + 2 * lane] = make_float2(ps0, ps1);
    }
    __syncthreads();
    if (tid < 128) {
        float* pt = (float*)s_tile;
        const float s = (pt[tid] + pt[128 + tid]) + (pt[256 + tid] + pt[384 + tid]);
        ws_sum[((size_t)(g * Nn + i) * 2 + half) * Kf + tid] = s;
    }

    // epilogue: +b2 (global), pad mask from ballot bits, store [g][m][i][j]
    const size_t attn_g = (size_t)g * Hh * (Nn * Nn) + (size_t)i * Nn + j0;
    const unsigned long long mOwn = (wq & 2) ? mB : mA;
#pragma unroll
    for (int jf = 0; jf < 2; ++jf) {
        const int jloc = wq * 32 + jf * 16 + l15;
        const int bit  = (wq & 1) * 32 + jf * 16 + l15;
        const bool keep = (mOwn >> bit) & 1ull;
#pragma unroll
        for (int mf = 0; mf < 2; ++mf) {
            const float4 b2v = *(const float4*)(b2 + mf * 16 + lhi * 4);
#pragma unroll
            for (int r = 0; r < 4; ++r) {
                const int m = mf * 16 + lhi * 4 + r;
                float v = acc2[mf][jf][r] + ((const float*)&b2v)[r];
                if (!keep) v = NEG_BIG;
                out_attn[attn_g + (size_t)m * (Nn * Nn) + jloc] = v;
            }
        }
    }
}

// ---------------------------------------------------------------------------
// Merge: [4096 x 128] @ we[128 x 768] + be.  Grid = 3 col-blocks x 256
// row-groups (768 blocks).
// ---------------------------------------------------------------------------
__global__ __launch_bounds__(256)
void graph3d_merge_kernel(const float* __restrict__ ws_sum,
                          const float* __restrict__ we,
                          const float* __restrict__ be,
                          float* __restrict__ out_merge)
{
    const int tid = threadIdx.x;
    const int bd  = blockIdx.x;          // column block: 0..2
    const int r0  = blockIdx.y * 16;     // row group
    __shared__ __align__(16) float s_rows[16][128];

#pragma unroll
    for (int p = 0; p < 8; ++p) {
        const int e = p * 256 + tid;
        const int r = e >> 7, k = e & 127;
        const size_t gi = (size_t)(r0 + r);
        s_rows[r][k] = ws_sum[(gi * 2 + 0) * Kf + k] + ws_sum[(gi * 2 + 1) * Kf + k];
    }
    __syncthreads();

    const int col = bd * 256 + tid;
    float acc[16];
#pragma unroll
    for (int r = 0; r < 16; ++r) acc[r] = 0.f;

    for (int k4 = 0; k4 < 32; ++k4) {
        const int k = k4 * 4;
        const float w0  = we[(k + 0) * Dd + col];
        const float w1v = we[(k + 1) * Dd + col];
        const float w2v = we[(k + 2) * Dd + col];
        const float w3  = we[(k + 3) * Dd + col];
#pragma unroll
        for (int r = 0; r < 16; ++r) {
            const float4 s = ((const float4*)&s_rows[r][0])[k4];
            acc[r] = fmaf(s.x, w0, acc[r]);
            acc[r] = fmaf(s.y, w1v, acc[r]);
            acc[r] = fmaf(s.z, w2v, acc[r]);
            acc[r] = fmaf(s.w, w3, acc[r]);
        }
    }

    const float b = be[col];
#pragma unroll
    for (int r = 0; r < 16; ++r)
        out_merge[(size_t)(r0 + r) * Dd + col] = acc[r] + b;
}

// ---------------------------------------------------------------------------
extern "C" void kernel_launch(void* const* d_in, const int* in_sizes, int n_in,
                              void* d_out, int out_size, void* d_ws, size_t ws_size,
                              hipStream_t stream) {
    const float* pos    = (const float*)d_in[0];
    const int*   x      = (const int*)  d_in[1];
    const int*   t      = (const int*)  d_in[2];
    const float* means  = (const float*)d_in[3];
    const float* stds   = (const float*)d_in[4];
    const float* mul_w  = (const float*)d_in[5];
    const float* bias_w = (const float*)d_in[6];
    const float* w1     = (const float*)d_in[7];
    const float* b1     = (const float*)d_in[8];
    const float* w2     = (const float*)d_in[9];
    const float* b2     = (const float*)d_in[10];
    const float* we     = (const float*)d_in[11];
    const float* be     = (const float*)d_in[12];

    float* out = (float*)d_out;
    float* out_dist  = out;
    float* out_delta = out + (size_t)Gn * Nn * Nn;
    float* out_attn  = out + (size_t)Gn * Nn * Nn * 4;
    float* out_merge = out + (size_t)Gn * Nn * Nn * 4 + (size_t)Gn * Hh * Nn * Nn;

    // ws: 4MB fp32 sum partials [g][i][half][k]; w1c 32KB; w2s 8KB; coef 32KB
    float* ws_sum = (float*)d_ws;
    char*  w1c  = (char*)d_ws + (size_t)Gn * Nn * 2 * Kf * 4;
    char*  w2s  = w1c + 4 * 8192;
    float4* coef = (float4*)(w2s + 8192);

    prep_kernel<<<18, 256, 0, stream>>>(w1, w2, t, means, stds, w1c, w2s, coef);

    dim3 gridA(2, Nn, Gn);
    graph3d_attn_kernel<<<gridA, 256, 0, stream>>>(
        pos, x, mul_w, bias_w, b1, b2, w1c, w2s, coef,
        ws_sum, out_dist, out_delta, out_attn);

    dim3 gridB(3, 256);
    graph3d_merge_kernel<<<gridB, 256, 0, stream>>>(
        ws_sum, we, be, out_merge);
}

// Round 9
// 121.301 us; speedup vs baseline: 1.6625x; 1.0650x over previous
//
#include <hip/hip_runtime.h>
#include <hip/hip_bf16.h>
#include <math.h>

#define Gn 16
#define Nn 256
#define Kf 128
#define Hh 32
#define Dd 768
#define NEG_BIG (-3.0e38f)
#define PAD_XG  (1.0e10f)                    // pad-fold: ef = exp2(-huge) = +0
#define INV_A 0.3989422804014327f            // 1/2.5066256735058273
#define NHALF_LOG2E (-0.7213475204444817f)   // -0.5*log2(e)
#define GELU_C (-2.4554669f)                 // -1.702*log2(e)

typedef __attribute__((ext_vector_type(8))) short bf16x8;
typedef __attribute__((ext_vector_type(4))) float f32x4;
typedef __attribute__((ext_vector_type(2))) float f32x2;

static __device__ __forceinline__ float fast_exp2(float x) {
#if __has_builtin(__builtin_amdgcn_exp2f)
    return __builtin_amdgcn_exp2f(x);
#else
    return exp2f(x);
#endif
}
static __device__ __forceinline__ float fast_rcp(float x) {
#if __has_builtin(__builtin_amdgcn_rcpf)
    return __builtin_amdgcn_rcpf(x);
#else
    return 1.0f / x;
#endif
}

static __device__ __forceinline__ unsigned short f2bf(float f) {
    union { float f; unsigned int u; } v; v.f = f;
    unsigned int r = v.u + 0x7FFF + ((v.u >> 16) & 1);   // RTNE
    return (unsigned short)(r >> 16);
}

// 16B global -> LDS DMA. LDS dest is wave-uniform base + lane*16.
static __device__ __forceinline__ void load_lds16(const void* g, void* l) {
    __builtin_amdgcn_global_load_lds(
        (const __attribute__((address_space(1))) unsigned int*)g,
        (__attribute__((address_space(3))) unsigned int*)l, 16, 0, 0);
}

// Copy an 8KB pre-swizzled image into LDS: wave wq covers [wq*1024, +1024)
// and [4096 + wq*1024, +1024), lane-linear 16B chunks.
static __device__ __forceinline__ void stage8k(const char* gsrc, char* lbase,
                                               int wq, int lane) {
    const char* g0 = gsrc + wq * 1024 + lane * 16;
    char* l0 = lbase + wq * 1024 + lane * 16;
    load_lds16(g0, l0);
    load_lds16(g0 + 4096, l0 + 4096);
}

// ---------------------------------------------------------------------------
// Prep: pre-swizzled LDS images of w1 (4 x 8KB ks-chunks) and w2 (8KB, full
// 16 slots), plus per-(g,k) gaussian coefficients {mean, Ak, Ck}.
//  w1 chunk ks, row n, slot s (0..3), elem e: k = ks*32+s*8+e
//    byte = ks*8192 + n*64 + ((s ^ (n&3))<<4) + 2e
//  w2 row m (0..31), slot s2 (0..15), elem e: k = s2*8+e
//    byte = m*256 + ((s2 ^ (m&7))<<4) + 2e
// ---------------------------------------------------------------------------
__global__ __launch_bounds__(256)
void prep_kernel(const float* __restrict__ w1, const float* __restrict__ w2,
                 const int* __restrict__ tarr, const float* __restrict__ means,
                 const float* __restrict__ stds,
                 char* __restrict__ w1c, char* __restrict__ w2s,
                 float4* __restrict__ coef)
{
    const int idx = blockIdx.x * 256 + threadIdx.x;
    if (idx < 2048) {                    // w1 chunks: (ks, n, s)
        const int ks = idx >> 9;
        const int n  = (idx >> 2) & 127;
        const int s  = idx & 3;
        unsigned short v[8];
#pragma unroll
        for (int e = 0; e < 8; ++e) {
            const int k = ks * 32 + s * 8 + e;
            v[e] = f2bf(w1[k * Kf + n]);
        }
        *(uint4*)(w1c + ks * 8192 + n * 64 + ((s ^ (n & 3)) << 4)) =
            *(const uint4*)v;
    } else if (idx < 2560) {             // w2: (m, s2) — full 16 slots
        const int e2 = idx - 2048;
        const int m = e2 >> 4, s2 = e2 & 15;
        unsigned short v[8];
#pragma unroll
        for (int e = 0; e < 8; ++e) {
            const int k = s2 * 8 + e;
            v[e] = f2bf(w2[k * Hh + m]);
        }
        *(uint4*)(w2s + m * 256 + ((s2 ^ (m & 7)) << 4)) = *(const uint4*)v;
    } else if (idx < 4608) {             // coef: (g, k)
        const int e3 = idx - 2560;
        const int g = e3 >> 7, k = e3 & 127;
        const int tg = tarr[g];
        const float mean = means[tg * Kf + k];
        const float sd   = fabsf(stds[tg * Kf + k]) + 1e-5f;
        const float inv  = 1.0f / sd;
        coef[g * Kf + k] =
            make_float4(mean, NHALF_LOG2E * inv * inv, log2f(inv * INV_A), 0.f);
    }
}

// ---------------------------------------------------------------------------
// Attn: block per (g, i, j-half of 128). LDS = tile 32KB + chunk 8KB = 40960B
// -> 4 blocks/CU. Phase-0 done once by tid<128; xg parked in tile row
// (quad*32+31) (overwritten only at phase-1 iter 31; within-wave LDS ops are
// in-order, so the read at iter 31 precedes the overwrite). Pad j folded as
// xg=1e10 -> ef = +0 exactly (sum matches reference's 0*ef; tile finite).
// Phase-1/GELU in packed-fp32 vector math. keep-mask re-read from atoms.
// Tile swizzle: byte ^= ((row&7)<<4) within each 256B row.
// ---------------------------------------------------------------------------
__global__ __launch_bounds__(256, 4)
void graph3d_attn_kernel(const float* __restrict__ pos,
                         const int* __restrict__ atoms,
                         const float* __restrict__ mul_w,
                         const float* __restrict__ bias_w,
                         const float* __restrict__ b1,
                         const float* __restrict__ b2,
                         const char* __restrict__ w1c,
                         const char* __restrict__ w2s,
                         const float4* __restrict__ coef,
                         float* __restrict__ ws_sum,
                         float* __restrict__ out_dist,
                         float* __restrict__ out_delta,
                         float* __restrict__ out_attn)
{
    const int tid  = threadIdx.x;
    const int half = blockIdx.x;       // j-half: 0 or 1
    const int i    = blockIdx.y;
    const int g    = blockIdx.z;
    const int j0   = half * 128;

    __shared__ __align__(16) unsigned short s_tile[128 * 128];  // ef then h
    __shared__ __align__(16) unsigned short s_chunk[4096];      // 8KB w1-chunk / w2

    const int lane = tid & 63, wq = tid >> 6;
    const int l15 = lane & 15, lhi = lane >> 4;

    // ---- phase 0 (tid<128): j = tid — dist/delta/xg once ----
    if (tid < 128) {
        const int ai = atoms[g * Nn + i];
        float pix = pos[(g * Nn + i) * 3 + 0];
        float piy = pos[(g * Nn + i) * 3 + 1];
        float piz = pos[(g * Nn + i) * 3 + 2];
        if (ai == 0) { pix = 0.f; piy = 0.f; piz = 0.f; }

        const int j  = j0 + tid;
        const int aj = atoms[g * Nn + j];
        float pjx = pos[(g * Nn + j) * 3 + 0];
        float pjy = pos[(g * Nn + j) * 3 + 1];
        float pjz = pos[(g * Nn + j) * 3 + 2];
        if (aj == 0) { pjx = 0.f; pjy = 0.f; pjz = 0.f; }
        const float dx = pjx - pix, dy = pjy - piy, dz = pjz - piz;
        const float sq = dx * dx + dy * dy + dz * dz;
        const float dist = (sq > 0.f) ? sqrtf(sq) : 0.f;
        const float inv_d = 1.f / (dist + 1e-5f);
        const size_t base = (size_t)(g * Nn + i) * Nn + j;
        out_dist[base] = dist;
        out_delta[base * 3 + 0] = dx * inv_d;
        out_delta[base * 3 + 1] = dy * inv_d;
        out_delta[base * 3 + 2] = dz * inv_d;
        const int et = ai * 128 + aj;
        float xg = fmaf(mul_w[et], dist, bias_w[et]);
        if (aj == 0) xg = PAD_XG;          // pad-fold: ef becomes exactly +0
        // park xg in tile row (quad*32+31), dword (j&31)
        *(float*)((char*)s_tile + (size_t)((tid >> 5) * 32 + 31) * 256 +
                  (tid & 31) * 4) = xg;
    }
    __syncthreads();

    // issue w1 chunk0 stage; drains at the phase-1-end barrier
    stage8k(w1c, (char*)s_chunk, wq, lane);

    // ---- phase 1: ef -> bf16 tile + packed fp32 j-sums ----
    // lane = k-pair (64 consecutive dwords per row -> conflict-free writes);
    // wave = own j-quadrant; xg via broadcast ds_read from row-31 scratch.
    f32x2 ps = (f32x2){0.f, 0.f};
    {
        const float4 c0 = coef[g * Kf + 2 * lane];
        const float4 c1 = coef[g * Kf + 2 * lane + 1];
        const f32x2 mn = (f32x2){c0.x, c1.x};
        const f32x2 Ak = (f32x2){c0.y, c1.y};
        const f32x2 Ck = (f32x2){c0.z, c1.z};
        char* rowbase = (char*)s_tile + wq * 32 * 256;
        const float* xgp = (const float*)((char*)s_tile + (wq * 32 + 31) * 256);
        const int colb = 4 * lane;
#pragma unroll 8
        for (int jj = 0; jj < 32; ++jj) {
            const float xgj = xgp[jj];                 // broadcast read
            f32x2 d = (f32x2){xgj, xgj} - mn;
            f32x2 t = Ak * (d * d) + Ck;               // pk fma chain
            const float e0 = fast_exp2(t.x);
            const float e1 = fast_exp2(t.y);
            ps += (f32x2){e0, e1};
            const __hip_bfloat162 p = __float22bfloat162_rn(make_float2(e0, e1));
            *(unsigned int*)(rowbase + jj * 256 + (colb ^ ((jj & 7) << 4))) =
                *(const unsigned int*)&p;
        }
    }
    __syncthreads();                       // tile complete + chunk0 staged

    // ---- phase 2: GEMM1  D1[n][j] = w1^T x ef^T (streamed 8KB chunks) ----
    const int jrow0 = wq * 32 + l15, jrow1 = jrow0 + 16;
    const char* tb0 = (const char*)s_tile + jrow0 * 256;
    const char* tb1 = (const char*)s_tile + jrow1 * 256;
    const int sw0 = (jrow0 & 7) << 4, sw1 = (jrow1 & 7) << 4;
    const int aoff = l15 * 64 + ((lhi ^ (l15 & 3)) << 4);

    f32x4 acc[8][2];
#pragma unroll
    for (int a = 0; a < 8; ++a)
#pragma unroll
        for (int b = 0; b < 2; ++b) acc[a][b] = (f32x4){0.f, 0.f, 0.f, 0.f};

#pragma unroll
    for (int ks = 0; ks < 4; ++ks) {
        if (ks) __syncthreads();           // chunk ks staged (vmcnt drained)
        const int kb = ks * 64 + lhi * 16;
        const bf16x8 b0  = *(const bf16x8*)(tb0 + (kb ^ sw0));
        const bf16x8 b1f = *(const bf16x8*)(tb1 + (kb ^ sw1));
        bf16x8 a0[4];
#pragma unroll
        for (int nf = 0; nf < 4; ++nf)
            a0[nf] = *(const bf16x8*)((const char*)s_chunk + nf * 1024 + aoff);
#pragma unroll
        for (int nf = 0; nf < 4; ++nf) {
            acc[nf][0] = __builtin_amdgcn_mfma_f32_16x16x32_bf16(a0[nf], b0,  acc[nf][0], 0, 0, 0);
            acc[nf][1] = __builtin_amdgcn_mfma_f32_16x16x32_bf16(a0[nf], b1f, acc[nf][1], 0, 0, 0);
        }
        bf16x8 a1[4];
#pragma unroll
        for (int nf = 0; nf < 4; ++nf)
            a1[nf] = *(const bf16x8*)((const char*)s_chunk + (nf + 4) * 1024 + aoff);
        __syncthreads();                   // all waves done reading chunk ks
        if (ks < 3) stage8k(w1c + (ks + 1) * 8192, (char*)s_chunk, wq, lane);
        else        stage8k(w2s, (char*)s_chunk, wq, lane);
#pragma unroll
        for (int nf = 0; nf < 4; ++nf) {
            acc[nf + 4][0] = __builtin_amdgcn_mfma_f32_16x16x32_bf16(a1[nf], b0,  acc[nf + 4][0], 0, 0, 0);
            acc[nf + 4][1] = __builtin_amdgcn_mfma_f32_16x16x32_bf16(a1[nf], b1f, acc[nf + 4][1], 0, 0, 0);
        }
    }

    // GELU epilogue: packed fp32 (+b1, exp2-sigmoid), packed b64 writes
#pragma unroll
    for (int nf = 0; nf < 8; ++nf) {
        const float4 bbv = *(const float4*)(b1 + nf * 16 + lhi * 4);
        const f32x4 bb = (f32x4){bbv.x, bbv.y, bbv.z, bbv.w};
        const int colb = 32 * nf + 8 * lhi;
#pragma unroll
        for (int jf = 0; jf < 2; ++jf) {
            const char* tb = jf ? tb1 : tb0;
            const int sw = jf ? sw1 : sw0;
            const f32x4 v = acc[nf][jf] + bb;
            const f32x4 arg = v * GELU_C;
            f32x4 den;
            den.x = fast_exp2(arg.x); den.y = fast_exp2(arg.y);
            den.z = fast_exp2(arg.z); den.w = fast_exp2(arg.w);
            den += 1.0f;
            f32x4 h;
            h.x = v.x * fast_rcp(den.x); h.y = v.y * fast_rcp(den.y);
            h.z = v.z * fast_rcp(den.z); h.w = v.w * fast_rcp(den.w);
            const __hip_bfloat162 p0 = __float22bfloat162_rn(make_float2(h.x, h.y));
            const __hip_bfloat162 p1 = __float22bfloat162_rn(make_float2(h.z, h.w));
            uint2 u;
            u.x = *(const unsigned int*)&p0;
            u.y = *(const unsigned int*)&p1;
            *(uint2*)(const_cast<char*>(tb) + (colb ^ sw)) = u;
        }
    }
    __syncthreads();                       // w2 image staged (vmcnt drained)

    // ---- phase 3: GEMM2  D[m][j] = w2^T x h^T ----
    f32x4 acc2[2][2];
#pragma unroll
    for (int a = 0; a < 2; ++a)
#pragma unroll
        for (int b = 0; b < 2; ++b) acc2[a][b] = (f32x4){0.f, 0.f, 0.f, 0.f};

#pragma unroll
    for (int ks = 0; ks < 4; ++ks) {
        const int kb = ks * 64 + lhi * 16;
        const bf16x8 bh0 = *(const bf16x8*)(tb0 + (kb ^ sw0));
        const bf16x8 bh1 = *(const bf16x8*)(tb1 + (kb ^ sw1));
#pragma unroll
        for (int mf = 0; mf < 2; ++mf) {
            const int m = mf * 16 + l15;
            const bf16x8 a2 = *(const bf16x8*)((const char*)s_chunk + m * 256 + (kb ^ ((m & 7) << 4)));
            acc2[mf][0] = __builtin_amdgcn_mfma_f32_16x16x32_bf16(a2, bh0, acc2[mf][0], 0, 0, 0);
            acc2[mf][1] = __builtin_amdgcn_mfma_f32_16x16x32_bf16(a2, bh1, acc2[mf][1], 0, 0, 0);
        }
    }

    // ---- k-sum reduce through the (now dead) tile, then ws_sum ----
    __syncthreads();                       // all waves done reading tile
    {
        float* pt = (float*)s_tile;        // 2KB scratch: [wq][2*kp]
        *(f32x2*)&pt[wq * 128 + 2 * lane] = ps;
    }
    __syncthreads();
    if (tid < 128) {
        const float* pt = (const float*)s_tile;
        const float s = (pt[tid] + pt[128 + tid]) + (pt[256 + tid] + pt[384 + tid]);
        ws_sum[((size_t)(g * Nn + i) * 2 + half) * Kf + tid] = s;
    }

    // epilogue: +b2 (global), keep re-read from atoms, store [g][m][i][j]
    const size_t attn_g = (size_t)g * Hh * (Nn * Nn) + (size_t)i * Nn + j0;
#pragma unroll
    for (int jf = 0; jf < 2; ++jf) {
        const int jloc = wq * 32 + jf * 16 + l15;
        const bool keep = atoms[g * Nn + j0 + jloc] != 0;
#pragma unroll
        for (int mf = 0; mf < 2; ++mf) {
            const float4 b2v = *(const float4*)(b2 + mf * 16 + lhi * 4);
            const f32x4 bv = (f32x4){b2v.x, b2v.y, b2v.z, b2v.w};
            const f32x4 v = acc2[mf][jf] + bv;
#pragma unroll
            for (int r = 0; r < 4; ++r) {
                const int m = mf * 16 + lhi * 4 + r;
                out_attn[attn_g + (size_t)m * (Nn * Nn) + jloc] =
                    keep ? v[r] : NEG_BIG;
            }
        }
    }
}

// ---------------------------------------------------------------------------
// Merge: [4096 x 128] @ we[128 x 768] + be.  Grid = 3 col-blocks x 256
// row-groups (768 blocks).
// ---------------------------------------------------------------------------
__global__ __launch_bounds__(256)
void graph3d_merge_kernel(const float* __restrict__ ws_sum,
                          const float* __restrict__ we,
                          const float* __restrict__ be,
                          float* __restrict__ out_merge)
{
    const int tid = threadIdx.x;
    const int bd  = blockIdx.x;          // column block: 0..2
    const int r0  = blockIdx.y * 16;     // row group
    __shared__ __align__(16) float s_rows[16][128];

#pragma unroll
    for (int p = 0; p < 8; ++p) {
        const int e = p * 256 + tid;
        const int r = e >> 7, k = e & 127;
        const size_t gi = (size_t)(r0 + r);
        s_rows[r][k] = ws_sum[(gi * 2 + 0) * Kf + k] + ws_sum[(gi * 2 + 1) * Kf + k];
    }
    __syncthreads();

    const int col = bd * 256 + tid;
    float acc[16];
#pragma unroll
    for (int r = 0; r < 16; ++r) acc[r] = 0.f;

    for (int k4 = 0; k4 < 32; ++k4) {
        const int k = k4 * 4;
        const float w0  = we[(k + 0) * Dd + col];
        const float w1v = we[(k + 1) * Dd + col];
        const float w2v = we[(k + 2) * Dd + col];
        const float w3  = we[(k + 3) * Dd + col];
#pragma unroll
        for (int r = 0; r < 16; ++r) {
            const float4 s = ((const float4*)&s_rows[r][0])[k4];
            acc[r] = fmaf(s.x, w0, acc[r]);
            acc[r] = fmaf(s.y, w1v, acc[r]);
            acc[r] = fmaf(s.z, w2v, acc[r]);
            acc[r] = fmaf(s.w, w3, acc[r]);
        }
    }

    const float b = be[col];
#pragma unroll
    for (int r = 0; r < 16; ++r)
        out_merge[(size_t)(r0 + r) * Dd + col] = acc[r] + b;
}

// ---------------------------------------------------------------------------
extern "C" void kernel_launch(void* const* d_in, const int* in_sizes, int n_in,
                              void* d_out, int out_size, void* d_ws, size_t ws_size,
                              hipStream_t stream) {
    const float* pos    = (const float*)d_in[0];
    const int*   x      = (const int*)  d_in[1];
    const int*   t      = (const int*)  d_in[2];
    const float* means  = (const float*)d_in[3];
    const float* stds   = (const float*)d_in[4];
    const float* mul_w  = (const float*)d_in[5];
    const float* bias_w = (const float*)d_in[6];
    const float* w1     = (const float*)d_in[7];
    const float* b1     = (const float*)d_in[8];
    const float* w2     = (const float*)d_in[9];
    const float* b2     = (const float*)d_in[10];
    const float* we     = (const float*)d_in[11];
    const float* be     = (const float*)d_in[12];

    float* out = (float*)d_out;
    float* out_dist  = out;
    float* out_delta = out + (size_t)Gn * Nn * Nn;
    float* out_attn  = out + (size_t)Gn * Nn * Nn * 4;
    float* out_merge = out + (size_t)Gn * Nn * Nn * 4 + (size_t)Gn * Hh * Nn * Nn;

    // ws: 4MB fp32 sum partials [g][i][half][k]; w1c 32KB; w2s 8KB; coef 32KB
    float* ws_sum = (float*)d_ws;
    char*  w1c  = (char*)d_ws + (size_t)Gn * Nn * 2 * Kf * 4;
    char*  w2s  = w1c + 4 * 8192;
    float4* coef = (float4*)(w2s + 8192);

    prep_kernel<<<18, 256, 0, stream>>>(w1, w2, t, means, stds, w1c, w2s, coef);

    dim3 gridA(2, Nn, Gn);
    graph3d_attn_kernel<<<gridA, 256, 0, stream>>>(
        pos, x, mul_w, bias_w, b1, b2, w1c, w2s, coef,
        ws_sum, out_dist, out_delta, out_attn);

    dim3 gridB(3, 256);
    graph3d_merge_kernel<<<gridB, 256, 0, stream>>>(
        ws_sum, we, be, out_merge);
}